// Round 1
// baseline (6225.348 us; speedup 1.0000x reference)
//
#include <hip/hip_runtime.h>
#include <hip/hip_bf16.h>
#include <math.h>

#define S_LEN 256
#define BATCH 64
#define EMB 300
#define HID 512
#define NCLS 46
#define NVAL 4
#define G4H 2048
#define EPSV 1e-8f

// ---------------- label norms: ln[c*NV+v] = ||label_embed[c,v,:]|| ----------------
__global__ void k_label_norm(const float* __restrict__ label, float* __restrict__ ln) {
    int r = blockIdx.x;              // 0..183
    int lane = threadIdx.x;          // 64
    const float* row = label + (size_t)r * EMB;
    float ss = 0.f;
    for (int e = lane; e < EMB; e += 64) { float v = row[e]; ss += v * v; }
    #pragma unroll
    for (int off = 32; off; off >>= 1) ss += __shfl_down(ss, off);
    if (lane == 0) ln[r] = sqrtf(ss);
}

// ---------------- gather embeddings + per-position norms ----------------
__global__ __launch_bounds__(256) void k_gather(const int* __restrict__ seq,
                                                const float* __restrict__ emb,
                                                float* __restrict__ embed,
                                                float* __restrict__ en) {
    int p = blockIdx.x * 4 + (threadIdx.x >> 6);   // position s*B+b, one wave each
    int lane = threadIdx.x & 63;
    int row = seq[p];
    const float4* src = (const float4*)(emb + (size_t)row * EMB);
    float4* dst = (float4*)(embed + (size_t)p * EMB);
    float ss = 0.f;
    for (int e = lane; e < EMB / 4; e += 64) {     // 75 float4
        float4 v = src[e];
        dst[e] = v;
        ss += v.x * v.x + v.y * v.y + v.z * v.z + v.w * v.w;
    }
    #pragma unroll
    for (int off = 32; off; off >>= 1) ss += __shfl_down(ss, off);
    if (lane == 0) en[p] = sqrtf(ss);
}

// ---------------- cosine similarity + max over (s, v) -> match[b][c] ----------------
__global__ __launch_bounds__(256) void k_cos(const float* __restrict__ embed,
                                             const float* __restrict__ en,
                                             const float* __restrict__ label,
                                             const float* __restrict__ ln,
                                             float* __restrict__ match) {
    int c = blockIdx.x, b = blockIdx.y;
    __shared__ float lab[NVAL][EMB];
    __shared__ float lns[NVAL];
    __shared__ float red[256];
    int tid = threadIdx.x;
    for (int i = tid; i < NVAL * EMB; i += 256) lab[i / EMB][i % EMB] = label[(size_t)c * NVAL * EMB + i];
    if (tid < NVAL) lns[tid] = ln[c * NVAL + tid];
    __syncthreads();
    int s = tid;  // 256 threads == 256 sequence positions
    const float4* erow = (const float4*)(embed + (size_t)(s * BATCH + b) * EMB);
    float d0 = 0, d1 = 0, d2 = 0, d3 = 0;
    for (int e = 0; e < EMB / 4; e++) {
        float4 v = erow[e];
        float4 l0 = *(const float4*)&lab[0][e * 4];
        float4 l1 = *(const float4*)&lab[1][e * 4];
        float4 l2 = *(const float4*)&lab[2][e * 4];
        float4 l3 = *(const float4*)&lab[3][e * 4];
        d0 += v.x * l0.x + v.y * l0.y + v.z * l0.z + v.w * l0.w;
        d1 += v.x * l1.x + v.y * l1.y + v.z * l1.z + v.w * l1.w;
        d2 += v.x * l2.x + v.y * l2.y + v.z * l2.z + v.w * l2.w;
        d3 += v.x * l3.x + v.y * l3.y + v.z * l3.z + v.w * l3.w;
    }
    float enb = en[s * BATCH + b];
    float m = d0 / fmaxf(enb * lns[0], EPSV);
    m = fmaxf(m, d1 / fmaxf(enb * lns[1], EPSV));
    m = fmaxf(m, d2 / fmaxf(enb * lns[2], EPSV));
    m = fmaxf(m, d3 / fmaxf(enb * lns[3], EPSV));
    red[tid] = m;
    __syncthreads();
    for (int st = 128; st; st >>= 1) {
        if (tid < st) red[tid] = fmaxf(red[tid], red[tid + st]);
        __syncthreads();
    }
    if (tid == 0) match[b * NCLS + c] = red[0];
}

// ---------------- transpose w[N][K] -> wT[K][N] ----------------
__global__ __launch_bounds__(256) void k_transpose(const float* __restrict__ w,
                                                   float* __restrict__ wT, int N, int K) {
    __shared__ float tile[64][65];
    int n0 = blockIdx.x * 64, k0 = blockIdx.y * 64;
    int tx = threadIdx.x & 63, ty = threadIdx.x >> 6;
    #pragma unroll
    for (int j = 0; j < 16; j++) {
        int n = ty * 16 + j;
        tile[n][tx] = w[(size_t)(n0 + n) * K + k0 + tx];
    }
    __syncthreads();
    #pragma unroll
    for (int j = 0; j < 16; j++) {
        int k = ty * 16 + j;
        wT[(size_t)(k0 + k) * N + n0 + tx] = tile[tx][k];
    }
}

// ---------------- big GEMM: Y[M][N] = X[M][K] @ W[N][K]^T + b1 + b2 ----------------
__global__ __launch_bounds__(256) void k_gemm(const float* __restrict__ X,
                                              const float* __restrict__ W,
                                              const float* __restrict__ b1,
                                              const float* __restrict__ b2,
                                              float* __restrict__ Y,
                                              int M, int N, int K) {
    __shared__ float Xs[16][132];
    __shared__ float Ws[16][132];
    int n0 = blockIdx.x * 128, m0 = blockIdx.y * 128;
    int tid = threadIdx.x;
    int tx = tid & 15, ty = tid >> 4;
    float acc[8][8] = {};
    for (int k0 = 0; k0 < K; k0 += 16) {
        #pragma unroll
        for (int i = 0; i < 8; i++) {
            int idx = i * 256 + tid;
            int r = idx >> 4, kk = idx & 15;
            int k = k0 + kk;
            Xs[kk][r] = (k < K) ? X[(size_t)(m0 + r) * K + k] : 0.f;
            Ws[kk][r] = (k < K) ? W[(size_t)(n0 + r) * K + k] : 0.f;
        }
        __syncthreads();
        #pragma unroll
        for (int kk = 0; kk < 16; kk++) {
            float a[8], w[8];
            *(float4*)&a[0] = *(const float4*)&Xs[kk][ty * 8];
            *(float4*)&a[4] = *(const float4*)&Xs[kk][ty * 8 + 4];
            *(float4*)&w[0] = *(const float4*)&Ws[kk][tx * 8];
            *(float4*)&w[4] = *(const float4*)&Ws[kk][tx * 8 + 4];
            #pragma unroll
            for (int i = 0; i < 8; i++)
                #pragma unroll
                for (int j = 0; j < 8; j++)
                    acc[i][j] += a[i] * w[j];
        }
        __syncthreads();
    }
    float bsum[8];
    #pragma unroll
    for (int j = 0; j < 8; j++) {
        int n = n0 + tx * 8 + j;
        bsum[j] = (b1 ? b1[n] : 0.f) + (b2 ? b2[n] : 0.f);
    }
    for (int i = 0; i < 8; i++) {
        float* yp = Y + (size_t)(m0 + ty * 8 + i) * N + n0 + tx * 8;
        #pragma unroll
        for (int j = 0; j < 8; j++) yp[j] = acc[i][j] + bsum[j];
    }
}

// ---------------- one LSTM step: gates = G[t] + h_prev @ w_hh^T, then pointwise ----------------
// block: jb (0..31) covers 16 hidden units (4 gates -> 64 gate-cols), bb (0..7) covers 8 batch.
// 256 threads = 4 waves; wave = k-chunk of 128; lane = gate-col.
__global__ __launch_bounds__(256) void k_gates(const float* __restrict__ wT,     // [512][2048]
                                               const float* __restrict__ Gt,     // [64][2048]
                                               const float* __restrict__ h_prev, // [64][512]
                                               float* __restrict__ c_buf,        // [64][512]
                                               float* __restrict__ h_out) {      // [64][512]
    __shared__ float hs[512 * 12];      // hs[k*12 + b], b in 0..7 (stride 12 for bank spread, 16B align)
    __shared__ float red[4 * 64 * 9];   // partials, stride 9
    __shared__ float gate_s[512];       // [col_local][b]
    int jb = blockIdx.x, bb = blockIdx.y;
    int tid = threadIdx.x;
    int lane = tid & 63, wid = tid >> 6;

    for (int i = tid; i < 8 * 512; i += 256) {
        int b = i >> 9, k = i & 511;
        hs[k * 12 + b] = h_prev[(size_t)(bb * 8 + b) * HID + k];
    }
    __syncthreads();

    int g = lane >> 4, jj = lane & 15;
    int col = g * 512 + jb * 16 + jj;
    float acc[8] = {0, 0, 0, 0, 0, 0, 0, 0};
    const float* wp = wT + (size_t)(wid * 128) * G4H + col;
    const float* hp = hs + (wid * 128) * 12;
    #pragma unroll 4
    for (int k = 0; k < 128; k++) {
        float w = wp[(size_t)k * G4H];
        float4 hA = *(const float4*)(hp + k * 12);
        float4 hB = *(const float4*)(hp + k * 12 + 4);
        acc[0] += w * hA.x; acc[1] += w * hA.y; acc[2] += w * hA.z; acc[3] += w * hA.w;
        acc[4] += w * hB.x; acc[5] += w * hB.y; acc[6] += w * hB.z; acc[7] += w * hB.w;
    }
    float* rp = red + (wid * 64 + lane) * 9;
    #pragma unroll
    for (int b = 0; b < 8; b++) rp[b] = acc[b];
    __syncthreads();

    for (int idx = tid; idx < 512; idx += 256) {
        int cl = idx >> 3, b = idx & 7;
        float s = red[cl * 9 + b] + red[(64 + cl) * 9 + b] + red[(128 + cl) * 9 + b] + red[(192 + cl) * 9 + b];
        int gg = cl >> 4, j2 = cl & 15;
        s += Gt[(size_t)(bb * 8 + b) * G4H + gg * 512 + jb * 16 + j2];
        gate_s[idx] = s;
    }
    __syncthreads();

    if (tid < 128) {
        int j2 = tid >> 3, b = tid & 7;
        float gi = gate_s[(0 * 16 + j2) * 8 + b];
        float gf = gate_s[(1 * 16 + j2) * 8 + b];
        float gc = gate_s[(2 * 16 + j2) * 8 + b];
        float go = gate_s[(3 * 16 + j2) * 8 + b];
        float iv = 1.f / (1.f + expf(-gi));
        float fv = 1.f / (1.f + expf(-gf));
        float gv = tanhf(gc);
        float ov = 1.f / (1.f + expf(-go));
        size_t ci = (size_t)(bb * 8 + b) * HID + jb * 16 + j2;
        float cv = fv * c_buf[ci] + iv * gv;
        c_buf[ci] = cv;
        h_out[ci] = ov * tanhf(cv);
    }
}

// ---------------- small GEMM: Y[m][n] = bias[n] + dot(X[m,:], W[n,:]) ----------------
__global__ void k_small(const float* __restrict__ X, const float* __restrict__ W,
                        const float* __restrict__ bias, float* __restrict__ Y,
                        int N, int K) {
    int m = blockIdx.x;
    int n = blockIdx.y * 64 + threadIdx.x;
    if (n >= N) return;
    const float* x = X + (size_t)m * K;
    const float* w = W + (size_t)n * K;
    float s = bias[n];
    for (int k = 0; k < K; k++) s += x[k] * w[k];
    Y[(size_t)m * N + n] = s;
}

// ---------------- final: out = [match, lout] @ pred_w^T + pred_b ----------------
__global__ void k_final(const float* __restrict__ match, const float* __restrict__ lout,
                        const float* __restrict__ W, const float* __restrict__ bias,
                        float* __restrict__ out) {
    int m = blockIdx.x;
    int n = threadIdx.x;
    if (n >= NCLS) return;
    const float* w = W + (size_t)n * (2 * NCLS);
    float s = bias[n];
    for (int k = 0; k < NCLS; k++) s += match[m * NCLS + k] * w[k];
    for (int k = 0; k < NCLS; k++) s += lout[m * NCLS + k] * w[NCLS + k];
    out[m * NCLS + n] = s;
}

extern "C" void kernel_launch(void* const* d_in, const int* in_sizes, int n_in,
                              void* d_out, int out_size, void* d_ws, size_t ws_size,
                              hipStream_t stream) {
    (void)in_sizes; (void)n_in; (void)out_size; (void)ws_size;
    const int*   seq    = (const int*)d_in[0];
    const float* emb    = (const float*)d_in[1];
    const float* w_ih0  = (const float*)d_in[2];
    const float* w_hh0  = (const float*)d_in[3];
    const float* b_ih0  = (const float*)d_in[4];
    const float* b_hh0  = (const float*)d_in[5];
    const float* w_ih1  = (const float*)d_in[6];
    const float* w_hh1  = (const float*)d_in[7];
    const float* b_ih1  = (const float*)d_in[8];
    const float* b_hh1  = (const float*)d_in[9];
    const float* lin_w  = (const float*)d_in[10];
    const float* lin_b  = (const float*)d_in[11];
    const float* out_w  = (const float*)d_in[12];
    const float* out_b  = (const float*)d_in[13];
    const float* pred_w = (const float*)d_in[14];
    const float* pred_b = (const float*)d_in[15];
    const float* label  = (const float*)d_in[16];

    float* ws = (float*)d_ws;
    size_t o = 0;
    float* wT0   = ws + o; o += (size_t)HID * G4H;            // 4 MB
    float* wT1   = ws + o; o += (size_t)HID * G4H;            // 4 MB
    float* embed = ws + o; o += (size_t)S_LEN * BATCH * EMB;  // 19.7 MB
    float* Gbuf  = ws + o; o += (size_t)S_LEN * BATCH * G4H;  // 134 MB
    float* h_all = ws + o; o += (size_t)S_LEN * BATCH * HID;  // 33.6 MB
    float* c_buf = ws + o; o += (size_t)BATCH * HID;
    float* z_h   = ws + o; o += (size_t)BATCH * HID;
    float* en    = ws + o; o += S_LEN * BATCH;
    float* ln    = ws + o; o += 256;
    float* match = ws + o; o += BATCH * NCLS;
    float* feat  = ws + o; o += (size_t)BATCH * HID;
    float* lout  = ws + o; o += BATCH * NCLS;

    // zero c state + zero-h buffer (adjacent)
    hipMemsetAsync(c_buf, 0, 2 * BATCH * HID * sizeof(float), stream);

    k_label_norm<<<NCLS * NVAL, 64, 0, stream>>>(label, ln);
    k_gather<<<S_LEN * BATCH / 4, 256, 0, stream>>>(seq, emb, embed, en);
    k_cos<<<dim3(NCLS, BATCH), 256, 0, stream>>>(embed, en, label, ln, match);
    k_transpose<<<dim3(G4H / 64, HID / 64), 256, 0, stream>>>(w_hh0, wT0, G4H, HID);
    k_transpose<<<dim3(G4H / 64, HID / 64), 256, 0, stream>>>(w_hh1, wT1, G4H, HID);

    // layer 0 input-gate precompute: G = embed @ w_ih0^T + b_ih0 + b_hh0
    k_gemm<<<dim3(G4H / 128, S_LEN * BATCH / 128), 256, 0, stream>>>(
        embed, w_ih0, b_ih0, b_hh0, Gbuf, S_LEN * BATCH, G4H, EMB);
    for (int t = 0; t < S_LEN; t++) {
        const float* hp = (t == 0) ? z_h : (h_all + (size_t)(t - 1) * BATCH * HID);
        k_gates<<<dim3(32, 8), 256, 0, stream>>>(
            wT0, Gbuf + (size_t)t * BATCH * G4H, hp, c_buf, h_all + (size_t)t * BATCH * HID);
    }

    // layer 1 input-gate precompute: G = h_all0 @ w_ih1^T + b_ih1 + b_hh1
    k_gemm<<<dim3(G4H / 128, S_LEN * BATCH / 128), 256, 0, stream>>>(
        h_all, w_ih1, b_ih1, b_hh1, Gbuf, S_LEN * BATCH, G4H, HID);
    hipMemsetAsync(c_buf, 0, BATCH * HID * sizeof(float), stream);
    for (int t = 0; t < S_LEN; t++) {
        const float* hp = (t == 0) ? z_h : (h_all + (size_t)(t - 1) * BATCH * HID);
        k_gates<<<dim3(32, 8), 256, 0, stream>>>(
            wT1, Gbuf + (size_t)t * BATCH * G4H, hp, c_buf, h_all + (size_t)t * BATCH * HID);
    }

    // heads
    k_small<<<dim3(BATCH, HID / 64), 64, 0, stream>>>(
        h_all + (size_t)(S_LEN - 1) * BATCH * HID, lin_w, lin_b, feat, HID, HID);
    k_small<<<dim3(BATCH, 1), 64, 0, stream>>>(feat, out_w, out_b, lout, NCLS, HID);
    k_final<<<BATCH, 64, 0, stream>>>(match, lout, pred_w, pred_b, (float*)d_out);
}

// Round 3
// 5681.224 us; speedup vs baseline: 1.0958x; 1.0958x over previous
//
#include <hip/hip_runtime.h>
#include <hip/hip_bf16.h>
#include <math.h>

#define S_LEN 256
#define BATCH 64
#define EMB 300
#define HID 512
#define NCLS 46
#define NVAL 4
#define G4H 2048
#define EPSV 1e-8f

// ---------------- label norms ----------------
__global__ void k_label_norm(const float* __restrict__ label, float* __restrict__ ln) {
    int r = blockIdx.x;
    int lane = threadIdx.x;
    const float* row = label + (size_t)r * EMB;
    float ss = 0.f;
    for (int e = lane; e < EMB; e += 64) { float v = row[e]; ss += v * v; }
    #pragma unroll
    for (int off = 32; off; off >>= 1) ss += __shfl_down(ss, off);
    if (lane == 0) ln[r] = sqrtf(ss);
}

// ---------------- gather embeddings + per-position norms ----------------
__global__ __launch_bounds__(256) void k_gather(const int* __restrict__ seq,
                                                const float* __restrict__ emb,
                                                float* __restrict__ embed,
                                                float* __restrict__ en) {
    int p = blockIdx.x * 4 + (threadIdx.x >> 6);
    int lane = threadIdx.x & 63;
    int row = seq[p];
    const float4* src = (const float4*)(emb + (size_t)row * EMB);
    float4* dst = (float4*)(embed + (size_t)p * EMB);
    float ss = 0.f;
    for (int e = lane; e < EMB / 4; e += 64) {
        float4 v = src[e];
        dst[e] = v;
        ss += v.x * v.x + v.y * v.y + v.z * v.z + v.w * v.w;
    }
    #pragma unroll
    for (int off = 32; off; off >>= 1) ss += __shfl_down(ss, off);
    if (lane == 0) en[p] = sqrtf(ss);
}

// ---------------- cosine similarity + max over (s, v) ----------------
__global__ __launch_bounds__(256) void k_cos(const float* __restrict__ embed,
                                             const float* __restrict__ en,
                                             const float* __restrict__ label,
                                             const float* __restrict__ ln,
                                             float* __restrict__ match) {
    int c = blockIdx.x, b = blockIdx.y;
    __shared__ float lab[NVAL][EMB];
    __shared__ float lns[NVAL];
    __shared__ float red[256];
    int tid = threadIdx.x;
    for (int i = tid; i < NVAL * EMB; i += 256) lab[i / EMB][i % EMB] = label[(size_t)c * NVAL * EMB + i];
    if (tid < NVAL) lns[tid] = ln[c * NVAL + tid];
    __syncthreads();
    int s = tid;
    const float4* erow = (const float4*)(embed + (size_t)(s * BATCH + b) * EMB);
    float d0 = 0, d1 = 0, d2 = 0, d3 = 0;
    for (int e = 0; e < EMB / 4; e++) {
        float4 v = erow[e];
        float4 l0 = *(const float4*)&lab[0][e * 4];
        float4 l1 = *(const float4*)&lab[1][e * 4];
        float4 l2 = *(const float4*)&lab[2][e * 4];
        float4 l3 = *(const float4*)&lab[3][e * 4];
        d0 += v.x * l0.x + v.y * l0.y + v.z * l0.z + v.w * l0.w;
        d1 += v.x * l1.x + v.y * l1.y + v.z * l1.z + v.w * l1.w;
        d2 += v.x * l2.x + v.y * l2.y + v.z * l2.z + v.w * l2.w;
        d3 += v.x * l3.x + v.y * l3.y + v.z * l3.z + v.w * l3.w;
    }
    float enb = en[s * BATCH + b];
    float m = d0 / fmaxf(enb * lns[0], EPSV);
    m = fmaxf(m, d1 / fmaxf(enb * lns[1], EPSV));
    m = fmaxf(m, d2 / fmaxf(enb * lns[2], EPSV));
    m = fmaxf(m, d3 / fmaxf(enb * lns[3], EPSV));
    red[tid] = m;
    __syncthreads();
    for (int st = 128; st; st >>= 1) {
        if (tid < st) red[tid] = fmaxf(red[tid], red[tid + st]);
        __syncthreads();
    }
    if (tid == 0) match[b * NCLS + c] = red[0];
}

// ---------------- big GEMM: Y = X @ W^T + b1 + b2 ----------------
__global__ __launch_bounds__(256) void k_gemm(const float* __restrict__ X,
                                              const float* __restrict__ W,
                                              const float* __restrict__ b1,
                                              const float* __restrict__ b2,
                                              float* __restrict__ Y,
                                              int M, int N, int K) {
    __shared__ float Xs[16][132];
    __shared__ float Ws[16][132];
    int n0 = blockIdx.x * 128, m0 = blockIdx.y * 128;
    int tid = threadIdx.x;
    int tx = tid & 15, ty = tid >> 4;
    float acc[8][8] = {};
    for (int k0 = 0; k0 < K; k0 += 16) {
        #pragma unroll
        for (int i = 0; i < 8; i++) {
            int idx = i * 256 + tid;
            int r = idx >> 4, kk = idx & 15;
            int k = k0 + kk;
            Xs[kk][r] = (k < K) ? X[(size_t)(m0 + r) * K + k] : 0.f;
            Ws[kk][r] = (k < K) ? W[(size_t)(n0 + r) * K + k] : 0.f;
        }
        __syncthreads();
        #pragma unroll
        for (int kk = 0; kk < 16; kk++) {
            float a[8], w[8];
            *(float4*)&a[0] = *(const float4*)&Xs[kk][ty * 8];
            *(float4*)&a[4] = *(const float4*)&Xs[kk][ty * 8 + 4];
            *(float4*)&w[0] = *(const float4*)&Ws[kk][tx * 8];
            *(float4*)&w[4] = *(const float4*)&Ws[kk][tx * 8 + 4];
            #pragma unroll
            for (int i = 0; i < 8; i++)
                #pragma unroll
                for (int j = 0; j < 8; j++)
                    acc[i][j] += a[i] * w[j];
        }
        __syncthreads();
    }
    float bsum[8];
    #pragma unroll
    for (int j = 0; j < 8; j++) {
        int n = n0 + tx * 8 + j;
        bsum[j] = (b1 ? b1[n] : 0.f) + (b2 ? b2[n] : 0.f);
    }
    for (int i = 0; i < 8; i++) {
        float* yp = Y + (size_t)(m0 + ty * 8 + i) * N + n0 + tx * 8;
        #pragma unroll
        for (int j = 0; j < 8; j++) yp[j] = acc[i][j] + bsum[j];
    }
}

__device__ __forceinline__ float bf16f(unsigned u32) { return __uint_as_float(u32); }
__device__ __forceinline__ float fsigm(float x) { return 1.f / (1.f + __expf(-x)); }
__device__ __forceinline__ float ftanh(float x) {
    float e2 = __expf(-2.f * x);
    return (1.f - e2) / (1.f + e2);
}

// ---------------- persistent LSTM layer ----------------
// grid 256 blocks (1 per CU), 256 threads. bid: jg = bid>>3 (16 hidden units), bg = bid&7 (8 batches).
// Weights (64 gate-cols x 512) as bf16 in LDS. h exchanged via agent-scope atomics through L3.
// Per-step sync: per-bg-group counter barrier (32 blocks each).
__global__ __launch_bounds__(256, 1) void k_lstm_persist(
    const float* __restrict__ w_hh,   // [2048][512]
    const float* __restrict__ G,      // [nsteps][64][2048]  (x@w_ih^T + b_ih + b_hh)
    float* __restrict__ hbase,        // ring=0: [nsteps][64][512]; ring=1: [2][64][512]
    int ring,
    int* __restrict__ cnt,            // [nsteps][8][16] ints, pre-zeroed
    int nsteps)
{
    __shared__ unsigned short wl[512 * 64];   // 64 KB, chunk-swizzled
    __shared__ float hl[8 * 516];             // 16.1 KB
    __shared__ float red[512 * 17];           // 34.8 KB
    __shared__ float gs[512];                 // gate sums [c*8+b]
    __shared__ float cs[128];                 // c state [j2*8+b]

    int bid = blockIdx.x;
    int jg = bid >> 3, bg = bid & 7;
    int tid = threadIdx.x;
    int co = tid & 7;              // col octet (8 cols)
    int bq = (tid >> 3) & 1;       // batch quad
    int kg = tid >> 4;             // k-group (32 k each)
    int c0 = co * 8, b0 = bq * 4, k0 = kg * 32;
    int sc = (co + kg) & 7;        // swizzled chunk slot

    // ---- stage weights -> bf16 LDS (one time) ----
    for (int i = 0; i < 32; i++) {
        int e4 = i * 256 + tid;            // float4 chunk id, 64 rows x 128 chunks
        int r = e4 >> 7;                   // col 0..63
        int kc = (e4 & 127) * 4;
        int gcol = (r >> 4) * 512 + jg * 16 + (r & 15);
        float4 w4 = *(const float4*)(w_hh + (size_t)gcol * 512 + kc);
        float wv[4] = {w4.x, w4.y, w4.z, w4.w};
        #pragma unroll
        for (int j = 0; j < 4; j++) {
            int k = kc + j;
            unsigned u = __float_as_uint(wv[j]);
            unsigned short us = (unsigned short)((u + 0x7FFFu + ((u >> 16) & 1u)) >> 16);
            wl[k * 64 + (((r >> 3) + (k >> 5)) & 7) * 8 + (r & 7)] = us;
        }
    }
    if (tid < 128) cs[tid] = 0.f;
    __syncthreads();

    const int HS = BATCH * HID;  // 32768
    for (int t = 0; t < nsteps; t++) {
        const float* Gt = G + (size_t)t * BATCH * G4H;
        // this thread's two outputs: o = c*8 + b
        int o0 = tid, o1 = tid + 256;
        int cA = o0 >> 3, bA = o0 & 7;
        int cB = o1 >> 3, bB = o1 & 7;
        float gA = Gt[(size_t)(bg * 8 + bA) * G4H + (cA >> 4) * 512 + jg * 16 + (cA & 15)];
        float gB = Gt[(size_t)(bg * 8 + bB) * G4H + (cB >> 4) * 512 + jg * 16 + (cB & 15)];

        float sA, sB;
        if (t > 0) {
            const float* hprev = hbase + (size_t)(ring ? ((t - 1) & 1) : (t - 1)) * HS;
            // stage h[t-1] slice (8 x 512) via agent-scope loads
            #pragma unroll
            for (int i = 0; i < 16; i++) {
                int idx = i * 256 + tid;
                int b = idx >> 9, k = idx & 511;
                float v = __hip_atomic_load((float*)hprev + (size_t)(bg * 8 + b) * HID + k,
                                            __ATOMIC_RELAXED, __HIP_MEMORY_SCOPE_AGENT);
                hl[b * 516 + k] = v;
            }
            __syncthreads();

            float acc[8][4];
            #pragma unroll
            for (int ci = 0; ci < 8; ci++)
                #pragma unroll
                for (int bi = 0; bi < 4; bi++) acc[ci][bi] = 0.f;

            #pragma unroll 8
            for (int kk = 0; kk < 32; kk++) {
                int k = k0 + kk;
                const unsigned* wd = (const unsigned*)(wl + k * 64 + sc * 8);
                unsigned d0 = wd[0], d1 = wd[1], d2 = wd[2], d3 = wd[3];
                float w0 = bf16f(d0 << 16), w1 = bf16f(d0 & 0xFFFF0000u);
                float w2 = bf16f(d1 << 16), w3 = bf16f(d1 & 0xFFFF0000u);
                float w4 = bf16f(d2 << 16), w5 = bf16f(d2 & 0xFFFF0000u);
                float w6 = bf16f(d3 << 16), w7 = bf16f(d3 & 0xFFFF0000u);
                float h0 = hl[(b0 + 0) * 516 + k];
                float h1 = hl[(b0 + 1) * 516 + k];
                float h2 = hl[(b0 + 2) * 516 + k];
                float h3 = hl[(b0 + 3) * 516 + k];
                acc[0][0] += w0 * h0; acc[0][1] += w0 * h1; acc[0][2] += w0 * h2; acc[0][3] += w0 * h3;
                acc[1][0] += w1 * h0; acc[1][1] += w1 * h1; acc[1][2] += w1 * h2; acc[1][3] += w1 * h3;
                acc[2][0] += w2 * h0; acc[2][1] += w2 * h1; acc[2][2] += w2 * h2; acc[2][3] += w2 * h3;
                acc[3][0] += w3 * h0; acc[3][1] += w3 * h1; acc[3][2] += w3 * h2; acc[3][3] += w3 * h3;
                acc[4][0] += w4 * h0; acc[4][1] += w4 * h1; acc[4][2] += w4 * h2; acc[4][3] += w4 * h3;
                acc[5][0] += w5 * h0; acc[5][1] += w5 * h1; acc[5][2] += w5 * h2; acc[5][3] += w5 * h3;
                acc[6][0] += w6 * h0; acc[6][1] += w6 * h1; acc[6][2] += w6 * h2; acc[6][3] += w6 * h3;
                acc[7][0] += w7 * h0; acc[7][1] += w7 * h1; acc[7][2] += w7 * h2; acc[7][3] += w7 * h3;
            }
            // partials -> LDS
            #pragma unroll
            for (int ci = 0; ci < 8; ci++)
                #pragma unroll
                for (int bi = 0; bi < 4; bi++)
                    red[((c0 + ci) * 8 + b0 + bi) * 17 + kg] = acc[ci][bi];
            __syncthreads();
            sA = gA; sB = gB;
            #pragma unroll
            for (int i = 0; i < 16; i++) { sA += red[o0 * 17 + i]; sB += red[o1 * 17 + i]; }
        } else {
            sA = gA; sB = gB;
        }
        gs[o0] = sA; gs[o1] = sB;
        __syncthreads();

        // pointwise + h store
        if (tid < 128) {
            int j2 = tid >> 3, b = tid & 7;
            float gi = gs[(0 * 16 + j2) * 8 + b];
            float gf = gs[(1 * 16 + j2) * 8 + b];
            float gc = gs[(2 * 16 + j2) * 8 + b];
            float go = gs[(3 * 16 + j2) * 8 + b];
            float cv = fsigm(gf) * cs[tid] + fsigm(gi) * ftanh(gc);
            cs[tid] = cv;
            float hv = fsigm(go) * ftanh(cv);
            float* hcur = hbase + (size_t)(ring ? (t & 1) : t) * HS;
            __hip_atomic_store(hcur + (size_t)(bg * 8 + b) * HID + jg * 16 + j2, hv,
                               __ATOMIC_RELAXED, __HIP_MEMORY_SCOPE_AGENT);
        }
        __syncthreads();   // drains all waves' stores (vmcnt) before arrival

        if (t < nsteps - 1) {
            int* ctr = cnt + (size_t)(t * 8 + bg) * 16;
            if (tid == 0) {
                __hip_atomic_fetch_add(ctr, 1, __ATOMIC_RELAXED, __HIP_MEMORY_SCOPE_AGENT);
                int guard = 1 << 21;
                while (__hip_atomic_load(ctr, __ATOMIC_RELAXED, __HIP_MEMORY_SCOPE_AGENT) < 32 && --guard)
                    __builtin_amdgcn_s_sleep(4);
            }
            __syncthreads();
        }
    }
}

// ---------------- small GEMM ----------------
__global__ void k_small(const float* __restrict__ X, const float* __restrict__ W,
                        const float* __restrict__ bias, float* __restrict__ Y,
                        int N, int K) {
    int m = blockIdx.x;
    int n = blockIdx.y * 64 + threadIdx.x;
    if (n >= N) return;
    const float* x = X + (size_t)m * K;
    const float* w = W + (size_t)n * K;
    float s = bias[n];
    for (int k = 0; k < K; k++) s += x[k] * w[k];
    Y[(size_t)m * N + n] = s;
}

// ---------------- final head ----------------
__global__ void k_final(const float* __restrict__ match, const float* __restrict__ lout,
                        const float* __restrict__ W, const float* __restrict__ bias,
                        float* __restrict__ out) {
    int m = blockIdx.x;
    int n = threadIdx.x;
    if (n >= NCLS) return;
    const float* w = W + (size_t)n * (2 * NCLS);
    float s = bias[n];
    for (int k = 0; k < NCLS; k++) s += match[m * NCLS + k] * w[k];
    for (int k = 0; k < NCLS; k++) s += lout[m * NCLS + k] * w[NCLS + k];
    out[m * NCLS + n] = s;
}

extern "C" void kernel_launch(void* const* d_in, const int* in_sizes, int n_in,
                              void* d_out, int out_size, void* d_ws, size_t ws_size,
                              hipStream_t stream) {
    (void)in_sizes; (void)n_in; (void)out_size; (void)ws_size;
    const int*   seq    = (const int*)d_in[0];
    const float* emb    = (const float*)d_in[1];
    const float* w_ih0  = (const float*)d_in[2];
    const float* w_hh0  = (const float*)d_in[3];
    const float* b_ih0  = (const float*)d_in[4];
    const float* b_hh0  = (const float*)d_in[5];
    const float* w_ih1  = (const float*)d_in[6];
    const float* w_hh1  = (const float*)d_in[7];
    const float* b_ih1  = (const float*)d_in[8];
    const float* b_hh1  = (const float*)d_in[9];
    const float* lin_w  = (const float*)d_in[10];
    const float* lin_b  = (const float*)d_in[11];
    const float* out_w  = (const float*)d_in[12];
    const float* out_b  = (const float*)d_in[13];
    const float* pred_w = (const float*)d_in[14];
    const float* pred_b = (const float*)d_in[15];
    const float* label  = (const float*)d_in[16];

    float* ws = (float*)d_ws;
    size_t o = 0;
    float* embed = ws + o; o += (size_t)S_LEN * BATCH * EMB;   // 19.7 MB
    float* Gbuf  = ws + o; o += (size_t)S_LEN * BATCH * G4H;   // 134 MB
    float* h_all = ws + o; o += (size_t)S_LEN * BATCH * HID;   // 33.6 MB
    float* hb2   = ws + o; o += (size_t)2 * BATCH * HID;       // ring for layer 1
    float* en    = ws + o; o += S_LEN * BATCH;
    float* ln    = ws + o; o += 256;
    float* match = ws + o; o += BATCH * NCLS;
    float* feat  = ws + o; o += (size_t)BATCH * HID;
    float* lout  = ws + o; o += BATCH * NCLS;
    int*   cnt   = (int*)(ws + o); o += 2 * 256 * 8 * 16;      // barrier counters

    hipMemsetAsync(cnt, 0, (size_t)2 * 256 * 8 * 16 * sizeof(int), stream);

    k_label_norm<<<NCLS * NVAL, 64, 0, stream>>>(label, ln);
    k_gather<<<S_LEN * BATCH / 4, 256, 0, stream>>>(seq, emb, embed, en);
    k_cos<<<dim3(NCLS, BATCH), 256, 0, stream>>>(embed, en, label, ln, match);

    // layer 0: G = embed @ w_ih0^T + b_ih0 + b_hh0, then persistent recurrence
    k_gemm<<<dim3(G4H / 128, S_LEN * BATCH / 128), 256, 0, stream>>>(
        embed, w_ih0, b_ih0, b_hh0, Gbuf, S_LEN * BATCH, G4H, EMB);
    k_lstm_persist<<<256, 256, 0, stream>>>(w_hh0, Gbuf, h_all, 0, cnt, S_LEN);

    // layer 1: G = h_all @ w_ih1^T + b_ih1 + b_hh1, then persistent recurrence (ring)
    k_gemm<<<dim3(G4H / 128, S_LEN * BATCH / 128), 256, 0, stream>>>(
        h_all, w_ih1, b_ih1, b_hh1, Gbuf, S_LEN * BATCH, G4H, HID);
    k_lstm_persist<<<256, 256, 0, stream>>>(w_hh1, Gbuf, hb2, 1, cnt + 256 * 8 * 16, S_LEN);

    // heads (layer-1 h[255] is in hb2 parity 1)
    k_small<<<dim3(BATCH, HID / 64), 64, 0, stream>>>(hb2 + (size_t)BATCH * HID, lin_w, lin_b, feat, HID, HID);
    k_small<<<dim3(BATCH, 1), 64, 0, stream>>>(feat, out_w, out_b, lout, NCLS, HID);
    k_final<<<BATCH, 64, 0, stream>>>(match, lout, pred_w, pred_b, (float*)d_out);
}